// Round 1
// baseline (77.573 us; speedup 1.0000x reference)
//
#include <hip/hip_runtime.h>
#include <hip/hip_bf16.h>
#include <math.h>

namespace {
constexpr int NSYS = 1024;     // BS*N_IND
constexpr int T    = 50;       // N_STEP
constexpr float ALPHA_C = 0.1f;
constexpr float G2      = 0.25f;   // GAMMA^2
constexpr int OU0  = 0;
constexpr int OU1  = NSYS * T;          // 51200
constexpr int OU2  = 2 * NSYS * T;      // 102400
constexpr int OEPS = 3 * NSYS * T;      // 153600
constexpr int OST  = OEPS + NSYS;       // 154624
}

// Cholesky of 3x3 SPD given lower-sym d = (d00,d10,d11,d20,d21,d22).
// Output f = (i00, l10, i11, l20, l21, i22): inverse diagonals + strict lower.
__device__ __forceinline__ void chol3(const float d[6], float f[6]) {
    float l00 = sqrtf(d[0]);
    float i00 = 1.0f / l00;
    float l10 = d[1] * i00;
    float l20 = d[3] * i00;
    float l11 = sqrtf(d[2] - l10 * l10);
    float i11 = 1.0f / l11;
    float l21 = (d[4] - l20 * l10) * i11;
    float l22 = sqrtf(d[5] - l20 * l20 - l21 * l21);
    float i22 = 1.0f / l22;
    f[0] = i00; f[1] = l10; f[2] = i11; f[3] = l20; f[4] = l21; f[5] = i22;
}

// q = F^{-1} v  (forward substitution)
__device__ __forceinline__ void fsub(const float f[6], const float v[3], float q[3]) {
    q[0] = v[0] * f[0];
    q[1] = (v[1] - f[1] * q[0]) * f[2];
    q[2] = (v[2] - f[3] * q[0] - f[4] * q[1]) * f[5];
}

// r = F^{-T} v  (back substitution)
__device__ __forceinline__ void bsub(const float f[6], const float v[3], float r[3]) {
    r[2] = v[2] * f[5];
    r[1] = (v[1] - f[4] * r[2]) * f[2];
    r[0] = (v[0] - f[1] * r[1] - f[3] * r[2]) * f[0];
}

__global__ __launch_bounds__(64) void ode_solve_kernel(
    const float* __restrict__ coeffs,   // (NSYS, T, 3)
    const float* __restrict__ rhs,      // (NSYS, T)
    const float* __restrict__ ivr,      // (NSYS, 2)
    const float* __restrict__ steps,    // (NSYS, T-1)
    float* __restrict__ out) {
    int s = blockIdx.x * blockDim.x + threadIdx.x;
    if (s >= NSYS) return;

    const float* C = coeffs + (size_t)s * T * 3;
    const float* R = rhs    + (size_t)s * T;
    const float* H = steps  + (size_t)s * (T - 1);

    // Per-thread scratch (compiler private segment): Cholesky factors,
    // arrow row z, forward-solve y. ~2.4 KB/thread.
    float F[T][6];
    float Z[T][3];
    float Y[T][3];

    float zprev[3] = {0.f, 0.f, 0.f};
    float yprev[3] = {0.f, 0.f, 0.f};
    float Fprev[6];
    float szz = 0.f;   // sum z.z
    float zy  = 0.f;   // sum z.y

    // ---------- forward sweep: block Cholesky + forward solve ----------
    #pragma unroll 1
    for (int t = 0; t < T; ++t) {
        float hp = (t > 0)     ? H[t - 1] : 0.f;
        float hc = (t < T - 1) ? H[t]     : 0.f;
        float c0 = C[3 * t], c1 = C[3 * t + 1], c2 = C[3 * t + 2];

        // Diagonal block D_t = alpha I + c c^T (+ IV) + g2*(AA(hc) + BB(hp))
        float d[6];
        d[0] = ALPHA_C + c0 * c0;
        d[1] = c0 * c1;
        d[2] = ALPHA_C + c1 * c1;
        d[3] = c0 * c2;
        d[4] = c1 * c2;
        d[5] = ALPHA_C + c2 * c2;
        float w[3] = {0.f, 0.f, 0.f};   // arrow column entries for this block
        if (t < T - 1) {
            float h = hc, h2 = h * h;
            d[0] += G2 * 2.f;
            d[1] += G2 * h;
            d[2] += G2 * (h2 + 2.f);
            d[3] += G2 * (0.5f * h2);
            d[4] += G2 * (0.5f * h2 * h + h);
            d[5] += G2 * (0.25f * h2 * h2 + h2);
            w[1] += G2 * h;
            w[2] += G2 * (0.5f * h2 + h);
        }
        if (t > 0) {
            float h = hp, h2 = h * h;
            d[0] += G2 * 2.f;
            d[1] -= G2 * h;
            d[2] += G2 * (h2 + 2.f);
            d[3] += G2 * (0.5f * h2);
            d[4] -= G2 * (0.5f * h2 * h + h);
            d[5] += G2 * (0.25f * h2 * h2 + h2);
            w[1] -= G2 * h;
            w[2] += G2 * (0.5f * h2 - h);
        }
        if (t == 0) { d[0] += 1.f; d[2] += 1.f; }   // A_iv^T A_iv

        // g_t = c_t * rhs_t (+ iv at t=0)
        float rt = R[t];
        float g[3] = {c0 * rt, c1 * rt, c2 * rt};
        if (t == 0) { g[0] += ivr[2 * s]; g[1] += ivr[2 * s + 1]; }

        if (t > 0) {
            // W = E_t^T = F_{t-1}^{-1} U_{t-1},  U = g2 * AB(hp)
            float h = hp, h2 = h * h;
            float U[3][3] = {
                {-2.f * G2,       h * G2,  -0.5f * h2 * G2},
                {  -h * G2,   -2.f * G2,          h * G2},
                {-0.5f * h2 * G2, -h * G2,            0.f}};
            float Wm[3][3];
            #pragma unroll
            for (int c = 0; c < 3; ++c) {
                float v[3] = {U[0][c], U[1][c], U[2][c]};
                float q[3];
                fsub(Fprev, v, q);
                Wm[0][c] = q[0]; Wm[1][c] = q[1]; Wm[2][c] = q[2];
            }
            // Schur: d -= W^T W
            d[0] -= Wm[0][0]*Wm[0][0] + Wm[1][0]*Wm[1][0] + Wm[2][0]*Wm[2][0];
            d[1] -= Wm[0][0]*Wm[0][1] + Wm[1][0]*Wm[1][1] + Wm[2][0]*Wm[2][1];
            d[2] -= Wm[0][1]*Wm[0][1] + Wm[1][1]*Wm[1][1] + Wm[2][1]*Wm[2][1];
            d[3] -= Wm[0][0]*Wm[0][2] + Wm[1][0]*Wm[1][2] + Wm[2][0]*Wm[2][2];
            d[4] -= Wm[0][1]*Wm[0][2] + Wm[1][1]*Wm[1][2] + Wm[2][1]*Wm[2][2];
            d[5] -= Wm[0][2]*Wm[0][2] + Wm[1][2]*Wm[1][2] + Wm[2][2]*Wm[2][2];
            // w -= W^T z_{t-1};  g -= W^T y_{t-1}
            #pragma unroll
            for (int i = 0; i < 3; ++i) {
                w[i] -= Wm[0][i]*zprev[0] + Wm[1][i]*zprev[1] + Wm[2][i]*zprev[2];
                g[i] -= Wm[0][i]*yprev[0] + Wm[1][i]*yprev[1] + Wm[2][i]*yprev[2];
            }
        }

        float f[6];
        chol3(d, f);
        float zt[3], yt[3];
        fsub(f, w, zt);
        fsub(f, g, yt);
        szz += zt[0]*zt[0] + zt[1]*zt[1] + zt[2]*zt[2];
        zy  += zt[0]*yt[0] + zt[1]*yt[1] + zt[2]*yt[2];
        #pragma unroll
        for (int k = 0; k < 6; ++k) { F[t][k] = f[k]; Fprev[k] = f[k]; }
        #pragma unroll
        for (int k = 0; k < 3; ++k) {
            Z[t][k] = zt[k]; Y[t][k] = yt[k];
            zprev[k] = zt[k]; yprev[k] = yt[k];
        }
    }

    // eps pivot: s_eps = alpha + gamma^2 * n_deriv_rows = 0.1 + 0.25*196 = 49.1
    float fe2  = (ALPHA_C + 49.f) - szz;
    float fe   = sqrtf(fe2);
    float yeps = -zy / fe;        // g_eps = 0
    float xeps = yeps / fe;

    // ---------- backward sweep ----------
    float xn[3] = {0.f, 0.f, 0.f};
    #pragma unroll 1
    for (int t = T - 1; t >= 0; --t) {
        float v[3];
        v[0] = Y[t][0] - Z[t][0] * xeps;
        v[1] = Y[t][1] - Z[t][1] * xeps;
        v[2] = Y[t][2] - Z[t][2] * xeps;
        if (t < T - 1) {
            // v -= E_{t+1}^T x_{t+1} = F_t^{-1} (U_t x_{t+1})
            float h = H[t], h2 = h * h;
            float U[3][3] = {
                {-2.f * G2,       h * G2,  -0.5f * h2 * G2},
                {  -h * G2,   -2.f * G2,          h * G2},
                {-0.5f * h2 * G2, -h * G2,            0.f}};
            float u[3];
            #pragma unroll
            for (int i = 0; i < 3; ++i)
                u[i] = U[i][0]*xn[0] + U[i][1]*xn[1] + U[i][2]*xn[2];
            float q[3];
            fsub(F[t], u, q);
            v[0] -= q[0]; v[1] -= q[1]; v[2] -= q[2];
        }
        float x[3];
        bsub(F[t], v, x);
        out[OU0 + s * T + t] = x[0];
        out[OU1 + s * T + t] = x[1];
        out[OU2 + s * T + t] = x[2];
        xn[0] = x[0]; xn[1] = x[1]; xn[2] = x[2];
    }
    out[OEPS + s] = xeps;
    #pragma unroll 1
    for (int t = 0; t < T - 1; ++t) out[OST + s * (T - 1) + t] = H[t];
}

extern "C" void kernel_launch(void* const* d_in, const int* in_sizes, int n_in,
                              void* d_out, int out_size, void* d_ws, size_t ws_size,
                              hipStream_t stream) {
    const float* coeffs = (const float*)d_in[0];
    const float* rhs    = (const float*)d_in[1];
    const float* iv_rhs = (const float*)d_in[2];
    const float* steps  = (const float*)d_in[3];
    float* out = (float*)d_out;
    dim3 grid(NSYS / 64), block(64);
    hipLaunchKernelGGL(ode_solve_kernel, grid, block, 0, stream,
                       coeffs, rhs, iv_rhs, steps, out);
}

// Round 2
// 60.579 us; speedup vs baseline: 1.2805x; 1.2805x over previous
//
#include <hip/hip_runtime.h>
#include <hip/hip_bf16.h>
#include <math.h>

namespace {
constexpr int NSYS = 1024;     // BS*N_IND
constexpr int T    = 50;       // N_STEP
constexpr float AL = 0.1f;     // ALPHA
constexpr float G2 = 0.25f;    // GAMMA^2
constexpr int OU0  = 0;
constexpr int OU1  = NSYS * T;          // 51200
constexpr int OU2  = 2 * NSYS * T;      // 102400
constexpr int OEPS = 3 * NSYS * T;      // 153600
constexpr int OST  = OEPS + NSYS;       // 154624
constexpr int BT   = 32;                // systems (threads) per block
}

__device__ __forceinline__ float rsq(float x) { return __builtin_amdgcn_rsqf(x); }
__device__ __forceinline__ float rcpf_(float x) { return __builtin_amdgcn_rcpf(x); }

// Cholesky of 3x3 SPD via rsqrt (we only ever need inverse diagonals).
// d = (d00,d10,d11,d20,d21,d22) -> f = (i00,l10,i11,l20,l21,i22)
__device__ __forceinline__ void chol3(const float d[6], float f[6]) {
    float i00 = rsq(d[0]);
    float l10 = d[1] * i00;
    float l20 = d[3] * i00;
    float i11 = rsq(d[2] - l10 * l10);
    float l21 = (d[4] - l20 * l10) * i11;
    float i22 = rsq(d[5] - l20 * l20 - l21 * l21);
    f[0] = i00; f[1] = l10; f[2] = i11; f[3] = l20; f[4] = l21; f[5] = i22;
}

__device__ __forceinline__ void fsub(const float f[6], const float v[3], float q[3]) {
    q[0] = v[0] * f[0];
    q[1] = (v[1] - f[1] * q[0]) * f[2];
    q[2] = (v[2] - f[3] * q[0] - f[4] * q[1]) * f[5];
}

__device__ __forceinline__ void bsub(const float f[6], const float v[3], float r[3]) {
    r[2] = v[2] * f[5];
    r[1] = (v[1] - f[4] * r[2]) * f[2];
    r[0] = (v[0] - f[1] * r[1] - f[3] * r[2]) * f[0];
}

__global__ __launch_bounds__(BT) void ode_solve_kernel(
    const float* __restrict__ coeffs,   // (NSYS, T, 3)
    const float* __restrict__ rhs,      // (NSYS, T)
    const float* __restrict__ ivr,      // (NSYS, 2)
    const float* __restrict__ steps,    // (NSYS, T-1)
    float* __restrict__ out) {
    // LDS: per-t solver state [t][field][lane] + staged inputs.
    __shared__ float sFZY[T * 12 * BT];      // 76800 B; fields 0-5=F, 6-8=Z, 9-11=Y
    __shared__ float sC[150 * BT];           // 19200 B; staged coeffs [sys][150]; reused as X out-stage
    __shared__ float sR[T * BT];             //  6400 B; [sys][50]
    __shared__ float sH[(T - 1) * BT];       //  6272 B; [sys][49]

    const int lane = threadIdx.x;
    const int s0   = blockIdx.x * BT;
    const int s    = s0 + lane;

    // ---- cooperative coalesced staging (float4) ----
    {
        const float4* gC = (const float4*)(coeffs + (size_t)s0 * 150);
        const float4* gR = (const float4*)(rhs    + (size_t)s0 * T);
        const float4* gH = (const float4*)(steps  + (size_t)s0 * (T - 1));
        float4* lC = (float4*)sC; float4* lR = (float4*)sR; float4* lH = (float4*)sH;
        for (int i = lane; i < 150 * BT / 4; i += BT) lC[i] = gC[i];
        for (int i = lane; i < T   * BT / 4; i += BT) lR[i] = gR[i];
        for (int i = lane; i < (T-1)*BT / 4; i += BT) lH[i] = gH[i];
    }
    __syncthreads();

    const int cbase = lane * 150;
    const int rbase = lane * T;
    const int hbase = lane * (T - 1);

    float Fprev[6];
    float zprev[3] = {0.f, 0.f, 0.f};
    float yprev[3] = {0.f, 0.f, 0.f};
    float szz = 0.f, zy = 0.f;

    // prefetch t=0 inputs
    float pc0 = sC[cbase + 0], pc1 = sC[cbase + 1], pc2 = sC[cbase + 2];
    float pr  = sR[rbase + 0];
    float phc = sH[hbase + 0];      // h_0 (T>1 always)
    float hp  = 0.f;

    // ---------- forward sweep ----------
    #pragma unroll 1
    for (int t = 0; t < T; ++t) {
        // prefetch next iteration's inputs (independent of this iteration's chain)
        float nc0 = 0.f, nc1 = 0.f, nc2 = 0.f, nr = 0.f, nhc = 0.f;
        if (t + 1 < T) {
            nc0 = sC[cbase + 3 * (t + 1) + 0];
            nc1 = sC[cbase + 3 * (t + 1) + 1];
            nc2 = sC[cbase + 3 * (t + 1) + 2];
            nr  = sR[rbase + t + 1];
            nhc = (t + 1 < T - 1) ? sH[hbase + t + 1] : 0.f;
        }
        float hc = phc;             // 0 at t=T-1 by construction
        float c0 = pc0, c1 = pc1, c2 = pc2;

        float d[6];
        d[0] = AL + c0 * c0;
        d[1] = c0 * c1;
        d[2] = AL + c1 * c1;
        d[3] = c0 * c2;
        d[4] = c1 * c2;
        d[5] = AL + c2 * c2;
        float w[3] = {0.f, 0.f, 0.f};
        if (t < T - 1) {
            float h = hc, h2 = h * h;
            d[0] += G2 * 2.f;
            d[1] += G2 * h;
            d[2] += G2 * (h2 + 2.f);
            d[3] += G2 * (0.5f * h2);
            d[4] += G2 * (0.5f * h2 * h + h);
            d[5] += G2 * (0.25f * h2 * h2 + h2);
            w[1] += G2 * h;
            w[2] += G2 * (0.5f * h2 + h);
        }
        if (t > 0) {
            float h = hp, h2 = h * h;
            d[0] += G2 * 2.f;
            d[1] -= G2 * h;
            d[2] += G2 * (h2 + 2.f);
            d[3] += G2 * (0.5f * h2);
            d[4] -= G2 * (0.5f * h2 * h + h);
            d[5] += G2 * (0.25f * h2 * h2 + h2);
            w[1] -= G2 * h;
            w[2] += G2 * (0.5f * h2 - h);
        }
        if (t == 0) { d[0] += 1.f; d[2] += 1.f; }

        float rt = pr;
        float g[3] = {c0 * rt, c1 * rt, c2 * rt};
        if (t == 0) { g[0] += ivr[2 * s]; g[1] += ivr[2 * s + 1]; }

        if (t > 0) {
            float h = hp, h2 = h * h;
            float U[3][3] = {
                {-2.f * G2,       h * G2,  -0.5f * h2 * G2},
                {  -h * G2,   -2.f * G2,          h * G2},
                {-0.5f * h2 * G2, -h * G2,            0.f}};
            float Wm[3][3];
            #pragma unroll
            for (int c = 0; c < 3; ++c) {
                float v[3] = {U[0][c], U[1][c], U[2][c]};
                float q[3];
                fsub(Fprev, v, q);
                Wm[0][c] = q[0]; Wm[1][c] = q[1]; Wm[2][c] = q[2];
            }
            d[0] -= Wm[0][0]*Wm[0][0] + Wm[1][0]*Wm[1][0] + Wm[2][0]*Wm[2][0];
            d[1] -= Wm[0][0]*Wm[0][1] + Wm[1][0]*Wm[1][1] + Wm[2][0]*Wm[2][1];
            d[2] -= Wm[0][1]*Wm[0][1] + Wm[1][1]*Wm[1][1] + Wm[2][1]*Wm[2][1];
            d[3] -= Wm[0][0]*Wm[0][2] + Wm[1][0]*Wm[1][2] + Wm[2][0]*Wm[2][2];
            d[4] -= Wm[0][1]*Wm[0][2] + Wm[1][1]*Wm[1][2] + Wm[2][1]*Wm[2][2];
            d[5] -= Wm[0][2]*Wm[0][2] + Wm[1][2]*Wm[1][2] + Wm[2][2]*Wm[2][2];
            #pragma unroll
            for (int i = 0; i < 3; ++i) {
                w[i] -= Wm[0][i]*zprev[0] + Wm[1][i]*zprev[1] + Wm[2][i]*zprev[2];
                g[i] -= Wm[0][i]*yprev[0] + Wm[1][i]*yprev[1] + Wm[2][i]*yprev[2];
            }
        }

        float f[6];
        chol3(d, f);
        float zt[3], yt[3];
        fsub(f, w, zt);
        fsub(f, g, yt);
        szz += zt[0]*zt[0] + zt[1]*zt[1] + zt[2]*zt[2];
        zy  += zt[0]*yt[0] + zt[1]*yt[1] + zt[2]*yt[2];

        const int tb = t * 12 * BT + lane;
        #pragma unroll
        for (int k = 0; k < 6; ++k) { sFZY[tb + k * BT] = f[k]; Fprev[k] = f[k]; }
        #pragma unroll
        for (int k = 0; k < 3; ++k) {
            sFZY[tb + (6 + k) * BT] = zt[k];
            sFZY[tb + (9 + k) * BT] = yt[k];
            zprev[k] = zt[k]; yprev[k] = yt[k];
        }

        hp = hc;
        pc0 = nc0; pc1 = nc1; pc2 = nc2; pr = nr; phc = nhc;
    }

    // eps pivot: g_ee = alpha + gamma^2 * 196 = 49.1;  xeps = -zy / fe^2
    float fe2  = (AL + 49.f) - szz;
    float xeps = -zy * rcpf_(fe2);

    // ---------- backward sweep (1-deep LDS prefetch pipeline) ----------
    float cur[12];
    {
        const int tb = (T - 1) * 12 * BT + lane;
        #pragma unroll
        for (int k = 0; k < 12; ++k) cur[k] = sFZY[tb + k * BT];
    }
    float xn0 = 0.f, xn1 = 0.f, xn2 = 0.f;
    float hcur = 0.f;   // h_t, unused at t=T-1
    #pragma unroll 1
    for (int t = T - 1; t >= 0; --t) {
        float nxt[12];
        float nh = 0.f;
        if (t > 0) {
            const int tb = (t - 1) * 12 * BT + lane;
            #pragma unroll
            for (int k = 0; k < 12; ++k) nxt[k] = sFZY[tb + k * BT];
            nh = sH[hbase + (t - 1)];
        } else {
            #pragma unroll
            for (int k = 0; k < 12; ++k) nxt[k] = 0.f;
        }

        float v[3];
        v[0] = cur[9]  - cur[6] * xeps;
        v[1] = cur[10] - cur[7] * xeps;
        v[2] = cur[11] - cur[8] * xeps;
        if (t < T - 1) {
            float h = hcur, h2 = h * h;
            float u[3];
            u[0] = -2.f * G2 * xn0 + h * G2 * xn1 - 0.5f * h2 * G2 * xn2;
            u[1] = -h * G2 * xn0 - 2.f * G2 * xn1 + h * G2 * xn2;
            u[2] = -0.5f * h2 * G2 * xn0 - h * G2 * xn1;
            float q[3];
            fsub(cur, u, q);
            v[0] -= q[0]; v[1] -= q[1]; v[2] -= q[2];
        }
        float x[3];
        bsub(cur, v, x);
        // stage outputs in LDS (reuse sC): [k][sys][t] flat = k*1600 + lane*50 + t
        sC[0 * T * BT + lane * T + t] = x[0];
        sC[1 * T * BT + lane * T + t] = x[1];
        sC[2 * T * BT + lane * T + t] = x[2];
        xn0 = x[0]; xn1 = x[1]; xn2 = x[2];

        hcur = nh;
        #pragma unroll
        for (int k = 0; k < 12; ++k) cur[k] = nxt[k];
    }
    out[OEPS + s] = xeps;
    __syncthreads();

    // ---------- coalesced copy-out ----------
    {
        float4* d0 = (float4*)(out + OU0 + (size_t)s0 * T);
        float4* d1 = (float4*)(out + OU1 + (size_t)s0 * T);
        float4* d2 = (float4*)(out + OU2 + (size_t)s0 * T);
        const float4* x0 = (const float4*)(sC + 0 * T * BT);
        const float4* x1 = (const float4*)(sC + 1 * T * BT);
        const float4* x2 = (const float4*)(sC + 2 * T * BT);
        for (int i = lane; i < T * BT / 4; i += BT) {
            d0[i] = x0[i]; d1[i] = x1[i]; d2[i] = x2[i];
        }
        float4* dh = (float4*)(out + OST + (size_t)s0 * (T - 1));
        const float4* xh = (const float4*)sH;
        for (int i = lane; i < (T - 1) * BT / 4; i += BT) dh[i] = xh[i];
    }
}

extern "C" void kernel_launch(void* const* d_in, const int* in_sizes, int n_in,
                              void* d_out, int out_size, void* d_ws, size_t ws_size,
                              hipStream_t stream) {
    const float* coeffs = (const float*)d_in[0];
    const float* rhs    = (const float*)d_in[1];
    const float* iv_rhs = (const float*)d_in[2];
    const float* steps  = (const float*)d_in[3];
    float* out = (float*)d_out;
    dim3 grid(NSYS / BT), block(BT);
    hipLaunchKernelGGL(ode_solve_kernel, grid, block, 0, stream,
                       coeffs, rhs, iv_rhs, steps, out);
}

// Round 3
// 12.609 us; speedup vs baseline: 6.1524x; 4.8046x over previous
//
#include <hip/hip_runtime.h>
#include <hip/hip_bf16.h>
#include <math.h>

namespace {
constexpr int NSYS = 1024;     // BS*N_IND
constexpr int T    = 50;       // N_STEP
constexpr float AL = 0.1f;     // ALPHA
constexpr float G2 = 0.25f;    // GAMMA^2
constexpr int OU0  = 0;
constexpr int OU1  = NSYS * T;          // 51200
constexpr int OU2  = 2 * NSYS * T;      // 102400
constexpr int OEPS = 3 * NSYS * T;      // 153600
constexpr int OST  = OEPS + NSYS;       // 154624
constexpr int WPB  = 4;                 // waves (systems) per block
}

__device__ __forceinline__ float rsq(float x)  { return __builtin_amdgcn_rsqf(x); }
__device__ __forceinline__ float rcp_(float x) { return __builtin_amdgcn_rcpf(x); }

// Cholesky of 3x3 SPD, d=(d00,d10,d11,d20,d21,d22) -> f=(i00,l10,i11,l20,l21,i22)
__device__ __forceinline__ void chol3(const float d[6], float f[6]) {
    float i00 = rsq(d[0]);
    float l10 = d[1] * i00;
    float l20 = d[3] * i00;
    float i11 = rsq(d[2] - l10 * l10);
    float l21 = (d[4] - l20 * l10) * i11;
    float i22 = rsq(d[5] - l20 * l20 - l21 * l21);
    f[0] = i00; f[1] = l10; f[2] = i11; f[3] = l20; f[4] = l21; f[5] = i22;
}

// o = D^{-1} v  via  F^{-T} F^{-1} v
__device__ __forceinline__ void solveD(const float f[6], float v0, float v1, float v2,
                                       float& o0, float& o1, float& o2) {
    float q0 = v0 * f[0];
    float q1 = (v1 - f[1] * q0) * f[2];
    float q2 = (v2 - f[3] * q0 - f[4] * q1) * f[5];
    o2 = q2 * f[5];
    o1 = (q1 - f[4] * o2) * f[2];
    o0 = (q0 - f[1] * o1 - f[3] * o2) * f[0];
}

__global__ __launch_bounds__(64 * WPB) void ode_pcr_kernel(
    const float* __restrict__ coeffs,   // (NSYS, T, 3)
    const float* __restrict__ rhs,      // (NSYS, T)
    const float* __restrict__ ivr,      // (NSYS, 2)
    const float* __restrict__ steps,    // (NSYS, T-1)
    float* __restrict__ out) {
    const int lane = threadIdx.x & 63;
    const int s    = blockIdx.x * WPB + (threadIdx.x >> 6);
    const int i    = lane;
    const bool act  = (i < T);
    const bool hasC = (i < T - 1);

    const float* Cp = coeffs + (size_t)s * T * 3;
    const float* Rp = rhs    + (size_t)s * T;
    const float* Hp = steps  + (size_t)s * (T - 1);

    // ---- per-lane inputs ----
    float c0 = 0.f, c1 = 0.f, c2 = 0.f, rr = 0.f, h = 0.f;
    if (act) { c0 = Cp[3*i]; c1 = Cp[3*i+1]; c2 = Cp[3*i+2]; rr = Rp[i]; }
    if (hasC) h = Hp[i];
    float iv0 = ivr[2*s], iv1 = ivr[2*s+1];     // uniform broadcast load
    float hm = __shfl(h, (lane + 63) & 63);      // h_{i-1}; garbage at i==0 (masked)

    // ---- initial block system: lane i owns block row i ----
    // D (6 sym), C = G[i,i+1] (9), A = G[i,i-1] = C_{i-1}^T (9), B = [g | w] (6)
    float d[6]  = {1.f, 0.f, 1.f, 0.f, 0.f, 1.f};   // identity for inactive lanes
    float cM[9] = {0.f,0.f,0.f,0.f,0.f,0.f,0.f,0.f,0.f};
    float aM[9] = {0.f,0.f,0.f,0.f,0.f,0.f,0.f,0.f,0.f};
    float bv[6] = {0.f,0.f,0.f,0.f,0.f,0.f};
    float wv1 = 0.f, wv2 = 0.f;                      // original arrow (w[0]=0 always)

    if (act) {
        d[0] = AL + c0*c0; d[1] = c0*c1; d[2] = AL + c1*c1;
        d[3] = c0*c2;      d[4] = c1*c2; d[5] = AL + c2*c2;
        if (i == 0) { d[0] += 1.f; d[2] += 1.f; }
        bv[0] = c0*rr; bv[1] = c1*rr; bv[2] = c2*rr;
        if (i == 0) { bv[0] += iv0; bv[1] += iv1; }
        if (hasC) {
            float h2 = h*h;
            d[0] += G2*2.f;           d[1] += G2*h;
            d[2] += G2*(h2+2.f);      d[3] += G2*0.5f*h2;
            d[4] += G2*(0.5f*h2*h+h); d[5] += G2*(0.25f*h2*h2+h2);
            wv1 += G2*h; wv2 += G2*(0.5f*h2 + h);
            cM[0] = -2.f*G2;      cM[1] = h*G2;    cM[2] = -0.5f*h2*G2;
            cM[3] = -h*G2;        cM[4] = -2.f*G2; cM[5] = h*G2;
            cM[6] = -0.5f*h2*G2;  cM[7] = -h*G2;   cM[8] = 0.f;
        }
        if (i > 0) {
            float h2 = hm*hm;
            d[0] += G2*2.f;             d[1] -= G2*hm;
            d[2] += G2*(h2+2.f);        d[3] += G2*0.5f*h2;
            d[4] -= G2*(0.5f*h2*hm+hm); d[5] += G2*(0.25f*h2*h2+h2);
            wv1 -= G2*hm; wv2 += G2*(0.5f*h2 - hm);
            // A = U(hm)^T
            aM[0] = -2.f*G2;      aM[1] = -hm*G2;   aM[2] = -0.5f*h2*G2;
            aM[3] = hm*G2;        aM[4] = -2.f*G2;  aM[5] = -hm*G2;
            aM[6] = -0.5f*h2*G2;  aM[7] = hm*G2;    aM[8] = 0.f;
        }
        bv[4] = wv1; bv[5] = wv2;   // second RHS = arrow vector w
    }

    // ---- block PCR: 6 levels (strides 1,2,4,8,16,32) ----
    #pragma unroll
    for (int lvl = 0; lvl < 6; ++lvl) {
        const int st = 1 << lvl;
        float f[6];
        chol3(d, f);
        float P[9], Q[9], Rv[6];
        // P = D^{-1} A (by columns), Q = D^{-1} C, Rv = D^{-1} [g|w]
        solveD(f, aM[0], aM[3], aM[6], P[0], P[3], P[6]);
        solveD(f, aM[1], aM[4], aM[7], P[1], P[4], P[7]);
        solveD(f, aM[2], aM[5], aM[8], P[2], P[5], P[8]);
        solveD(f, cM[0], cM[3], cM[6], Q[0], Q[3], Q[6]);
        solveD(f, cM[1], cM[4], cM[7], Q[1], Q[4], Q[7]);
        solveD(f, cM[2], cM[5], cM[8], Q[2], Q[5], Q[8]);
        solveD(f, bv[0], bv[1], bv[2], Rv[0], Rv[1], Rv[2]);
        solveD(f, bv[3], bv[4], bv[5], Rv[3], Rv[4], Rv[5]);

        const int up = (lane - st) & 63;
        const int dn = (lane + st) & 63;
        float Qu[9], Pu[9], Pd[9], Qd[9], Ru[6], Rd[6];
        #pragma unroll
        for (int k = 0; k < 9; ++k) {
            Qu[k] = __shfl(Q[k], up);
            Pu[k] = __shfl(P[k], up);
            Pd[k] = __shfl(P[k], dn);
            Qd[k] = __shfl(Q[k], dn);
        }
        #pragma unroll
        for (int k = 0; k < 6; ++k) {
            Ru[k] = __shfl(Rv[k], up);
            Rd[k] = __shfl(Rv[k], dn);
        }
        // D' = D - A*Qu - C*Pd  (lower-sym entries; exact-symmetric in infinite precision)
        float nd[6];
        nd[0] = d[0] - (aM[0]*Qu[0]+aM[1]*Qu[3]+aM[2]*Qu[6]) - (cM[0]*Pd[0]+cM[1]*Pd[3]+cM[2]*Pd[6]);
        nd[1] = d[1] - (aM[3]*Qu[0]+aM[4]*Qu[3]+aM[5]*Qu[6]) - (cM[3]*Pd[0]+cM[4]*Pd[3]+cM[5]*Pd[6]);
        nd[2] = d[2] - (aM[3]*Qu[1]+aM[4]*Qu[4]+aM[5]*Qu[7]) - (cM[3]*Pd[1]+cM[4]*Pd[4]+cM[5]*Pd[7]);
        nd[3] = d[3] - (aM[6]*Qu[0]+aM[7]*Qu[3]+aM[8]*Qu[6]) - (cM[6]*Pd[0]+cM[7]*Pd[3]+cM[8]*Pd[6]);
        nd[4] = d[4] - (aM[6]*Qu[1]+aM[7]*Qu[4]+aM[8]*Qu[7]) - (cM[6]*Pd[1]+cM[7]*Pd[4]+cM[8]*Pd[7]);
        nd[5] = d[5] - (aM[6]*Qu[2]+aM[7]*Qu[5]+aM[8]*Qu[8]) - (cM[6]*Pd[2]+cM[7]*Pd[5]+cM[8]*Pd[8]);
        // B' = B - A*Ru - C*Rd  (per RHS)
        float nb[6];
        nb[0] = bv[0] - (aM[0]*Ru[0]+aM[1]*Ru[1]+aM[2]*Ru[2]) - (cM[0]*Rd[0]+cM[1]*Rd[1]+cM[2]*Rd[2]);
        nb[1] = bv[1] - (aM[3]*Ru[0]+aM[4]*Ru[1]+aM[5]*Ru[2]) - (cM[3]*Rd[0]+cM[4]*Rd[1]+cM[5]*Rd[2]);
        nb[2] = bv[2] - (aM[6]*Ru[0]+aM[7]*Ru[1]+aM[8]*Ru[2]) - (cM[6]*Rd[0]+cM[7]*Rd[1]+cM[8]*Rd[2]);
        nb[3] = bv[3] - (aM[0]*Ru[3]+aM[1]*Ru[4]+aM[2]*Ru[5]) - (cM[0]*Rd[3]+cM[1]*Rd[4]+cM[2]*Rd[5]);
        nb[4] = bv[4] - (aM[3]*Ru[3]+aM[4]*Ru[4]+aM[5]*Ru[5]) - (cM[3]*Rd[3]+cM[4]*Rd[4]+cM[5]*Rd[5]);
        nb[5] = bv[5] - (aM[6]*Ru[3]+aM[7]*Ru[4]+aM[8]*Ru[5]) - (cM[6]*Rd[3]+cM[7]*Rd[4]+cM[8]*Rd[5]);
        // A' = -A*Pu ; C' = -C*Qd
        float na[9], nc[9];
        #pragma unroll
        for (int a = 0; a < 3; ++a) {
            #pragma unroll
            for (int bcol = 0; bcol < 3; ++bcol) {
                na[3*a+bcol] = -(aM[3*a+0]*Pu[bcol] + aM[3*a+1]*Pu[3+bcol] + aM[3*a+2]*Pu[6+bcol]);
                nc[3*a+bcol] = -(cM[3*a+0]*Qd[bcol] + cM[3*a+1]*Qd[3+bcol] + cM[3*a+2]*Qd[6+bcol]);
            }
        }
        #pragma unroll
        for (int k = 0; k < 6; ++k) { d[k] = nd[k]; bv[k] = nb[k]; }
        #pragma unroll
        for (int k = 0; k < 9; ++k) { aM[k] = na[k]; cM[k] = nc[k]; }
    }

    // ---- decoupled: y = D^{-1} [g|w] per lane ----
    float f[6];
    chol3(d, f);
    float yg0, yg1, yg2, yw0, yw1, yw2;
    solveD(f, bv[0], bv[1], bv[2], yg0, yg1, yg2);
    solveD(f, bv[3], bv[4], bv[5], yw0, yw1, yw2);

    // ---- arrow (eps) Schur: reduce w·yw and w·yg over lanes ----
    float s1 = wv1 * yw1 + wv2 * yw2;   // w[0]=0
    float s2 = wv1 * yg1 + wv2 * yg2;
    #pragma unroll
    for (int m = 1; m < 64; m <<= 1) {
        s1 += __shfl_xor(s1, m);
        s2 += __shfl_xor(s2, m);
    }
    float xeps = -s2 * rcp_((AL + 49.f) - s1);

    float x0 = yg0 - yw0 * xeps;
    float x1 = yg1 - yw1 * xeps;
    float x2 = yg2 - yw2 * xeps;

    // ---- outputs (lane index == t, coalesced within each system row) ----
    if (act) {
        out[OU0 + s * T + i] = x0;
        out[OU1 + s * T + i] = x1;
        out[OU2 + s * T + i] = x2;
    }
    if (i == 0) out[OEPS + s] = xeps;
    if (hasC)   out[OST + s * (T - 1) + i] = h;
}

extern "C" void kernel_launch(void* const* d_in, const int* in_sizes, int n_in,
                              void* d_out, int out_size, void* d_ws, size_t ws_size,
                              hipStream_t stream) {
    const float* coeffs = (const float*)d_in[0];
    const float* rhs    = (const float*)d_in[1];
    const float* iv_rhs = (const float*)d_in[2];
    const float* steps  = (const float*)d_in[3];
    float* out = (float*)d_out;
    dim3 grid(NSYS / WPB), block(64 * WPB);
    hipLaunchKernelGGL(ode_pcr_kernel, grid, block, 0, stream,
                       coeffs, rhs, iv_rhs, steps, out);
}